// Round 2
// baseline (322.500 us; speedup 1.0000x reference)
//
#include <hip/hip_runtime.h>

typedef __attribute__((ext_vector_type(8))) short s16x8;
typedef __attribute__((ext_vector_type(4))) float f32x4;
typedef unsigned short u16;
typedef unsigned int   u32;

#define MFMA16(a,b,c) __builtin_amdgcn_mfma_f32_16x16x32_bf16((a),(b),(c),0,0,0)

__device__ __forceinline__ float bf2f(u16 u){
  u32 x = ((u32)u) << 16; float f; __builtin_memcpy(&f, &x, 4); return f;
}
__device__ __forceinline__ u16 f2bf(float f){
  u32 x; __builtin_memcpy(&x, &f, 4);
  x += 0x7FFFu + ((x >> 16) & 1u);   // round-to-nearest-even
  return (u16)(x >> 16);
}
__device__ __forceinline__ u32 pack2(float a, float b){
  return (u32)f2bf(a) | ((u32)f2bf(b) << 16);
}

// ---------------------------------------------------------------------------
// GAT kernel: 3 layers fused. One block = 4 batch elements, 256 threads.
// wave w = head w for matmul1; wave w = local batch bl=w for matmul2.
// LDS layouts (bf16):
//   xs  [112 rows][stride 40]  rows = bl*26+n, cols k=f (26 valid, pad 0)
//   WsT [4 heads][32 rows][stride 40] rows o: 0..25 = W[:, o] (k=f),
//        row 26 = W@a_src, row 27 = W@a_dst, rows 28..31 = 0
//   hsT [4 heads][32 rows o][stride 108] cols gr = bl*26+n  (h transposed)
//   hsT padding (rows 28..31, cols 104..107, tail) zeroed ONCE at start and
//   never written again -> k>=26 A-operand reads are finite, B there is 0.
// ---------------------------------------------------------------------------
__global__ __launch_bounds__(256) void gat_kernel(
    const float* __restrict__ x, const float* __restrict__ W,
    const float* __restrict__ a_src, const float* __restrict__ a_dst,
    u16* __restrict__ xf)
{
  __shared__ u16 xs [112*40];
  __shared__ u16 WsT[4*32*40];
  __shared__ u16 hsT[4*32*108 + 16];  // +16 tail pad for frag over-read

  const int tid  = threadIdx.x;
  const int w    = tid >> 6;
  const int lane = tid & 63;
  const int q    = lane >> 4;
  const int lm   = lane & 15;
  const int b0   = blockIdx.x * 4;

  // zero ALL of hsT once (padding regions are never written afterwards)
  for (int e = tid; e < 4*32*108 + 16; e += 256) hsT[e] = 0;
  // zero xs padding: cols 26..39 (all rows), rows 104..111 (cols 0..25)
  for (int e = tid; e < 112*14; e += 256){ int r = e/14, c = 26 + e%14; xs[r*40 + c] = 0; }
  for (int e = tid; e < 8*26;  e += 256){ int r = 104 + e/26, c = e%26; xs[r*40 + c] = 0; }
  // load x (fp32 -> bf16)
  for (int e = tid; e < 4*676; e += 256){
    int r = e % 676, n = r / 26, f = r % 26, b = e / 676;
    xs[(b*26 + n)*40 + f] = f2bf(x[b0*676 + e]);
  }

  for (int l = 0; l < 3; ++l){
    __syncthreads();
    // ---- load W (transposed, augmented with W@a_src / W@a_dst) ----
    const float* Wl  = W     + l*(4*26*26);
    const float* asl = a_src + l*(4*26);
    const float* adl = a_dst + l*(4*26);
    for (int e = tid; e < 4*4*40; e += 256){   // rows 28..31 = 0
      int h = e/160, r = e%160, o = 28 + r/40, c = r%40;
      WsT[(h*32 + o)*40 + c] = 0;
    }
    for (int e = tid; e < 4*28*14; e += 256){  // cols 26..39 = 0
      int h = e/392, r = e%392, o = r/14, c = 26 + r%14;
      WsT[(h*32 + o)*40 + c] = 0;
    }
    for (int e = tid; e < 4*676; e += 256){    // WsT[h][o][f] = W[h][f][o]
      int h = e/676, r = e%676, f = r/26, o = r%26;
      WsT[(h*32 + o)*40 + f] = f2bf(Wl[e]);
    }
    if (tid < 208){                            // combined attention columns
      int sel = tid/104, r = tid%104, h = r/26, f = r%26;
      const float* av = (sel ? adl : asl) + h*26;
      const float* wr = Wl + (h*26 + f)*26;
      float acc = 0.f;
      #pragma unroll
      for (int o = 0; o < 26; ++o) acc += wr[o]*av[o];
      WsT[(h*32 + 26 + sel)*40 + f] = f2bf(acc);
    }
    __syncthreads();

    // ---- matmul1: h_aug = x @ W_aug  (head = w) ----
    {
      s16x8 bfr0 = *(const s16x8*)&WsT[(w*32      + lm)*40 + q*8];
      s16x8 bfr1 = *(const s16x8*)&WsT[(w*32 + 16 + lm)*40 + q*8];
      #pragma unroll
      for (int t = 0; t < 7; ++t){
        s16x8 af = *(const s16x8*)&xs[(t*16 + lm)*40 + q*8];
        f32x4 z = {0.f,0.f,0.f,0.f};
        f32x4 d0 = MFMA16(af, bfr0, z);
        f32x4 d1 = MFMA16(af, bfr1, z);
        int gr0 = t*16 + q*4;
        if (gr0 < 104){
          { uint2 uu; uu.x = pack2(d0[0], d0[1]); uu.y = pack2(d0[2], d0[3]);
            *(uint2*)&hsT[(w*32 + lm)*108 + gr0] = uu; }
          if (lm < 12){
            uint2 uu; uu.x = pack2(d1[0], d1[1]); uu.y = pack2(d1[2], d1[3]);
            *(uint2*)&hsT[(w*32 + 16 + lm)*108 + gr0] = uu; }
        }
      }
    }
    __syncthreads();

    // ---- matmul2: out^T = h^T @ alpha^T, softmax built in-register (bl = w)
    {
      f32x4 acc00 = {0,0,0,0}, acc01 = acc00, acc10 = acc00, acc11 = acc00;
      const int j0 = q*8;
      #pragma unroll
      for (int h = 0; h < 4; ++h){
        s16x8 am0, am1;
        {
          int base = (h*32 + lm)*108 + w*26 + j0;
          uint4 uu = { *(const u32*)&hsT[base],   *(const u32*)&hsT[base+2],
                       *(const u32*)&hsT[base+4], *(const u32*)&hsT[base+6] };
          am0 = __builtin_bit_cast(s16x8, uu);
          base = (h*32 + 16 + lm)*108 + w*26 + j0;
          uint4 vv = { *(const u32*)&hsT[base],   *(const u32*)&hsT[base+2],
                       *(const u32*)&hsT[base+4], *(const u32*)&hsT[base+6] };
          am1 = __builtin_bit_cast(s16x8, vv);
        }
        float sd[8];
        {
          int base = (h*32 + 27)*108 + w*26 + j0;
          #pragma unroll
          for (int u = 0; u < 4; ++u){
            u32 v = *(const u32*)&hsT[base + 2*u];
            sd[2*u]   = bf2f((u16)(v & 0xFFFFu));
            sd[2*u+1] = bf2f((u16)(v >> 16));
          }
        }
        #pragma unroll
        for (int nt = 0; nt < 2; ++nt){
          int i = nt*16 + lm;
          float si = (i < 26) ? bf2f(hsT[(h*32 + 26)*108 + w*26 + i]) : 0.f;
          float p[8]; float loc = 0.f;
          #pragma unroll
          for (int jj = 0; jj < 8; ++jj){
            float e = si + sd[jj];
            e = (e >= 0.f) ? e : 0.2f*e;            // leaky_relu 0.2
            float pv = ((j0 + jj) < 26 && i < 26) ? __expf(e) : 0.f;
            p[jj] = pv; loc += pv;
          }
          float tot = loc;
          tot += __shfl_xor(tot, 16);
          tot += __shfl_xor(tot, 32);
          float rinv = (tot > 0.f) ? 1.f / tot : 0.f;  // no inf/NaN ever
          uint4 bu = { pack2(p[0]*rinv, p[1]*rinv), pack2(p[2]*rinv, p[3]*rinv),
                       pack2(p[4]*rinv, p[5]*rinv), pack2(p[6]*rinv, p[7]*rinv) };
          s16x8 bfrag = __builtin_bit_cast(s16x8, bu);
          if (nt == 0){ acc00 = MFMA16(am0, bfrag, acc00);
                        acc10 = MFMA16(am1, bfrag, acc10); }
          else        { acc01 = MFMA16(am0, bfrag, acc01);
                        acc11 = MFMA16(am1, bfrag, acc11); }
        }
      }
      // epilogue: mean heads (x0.25), ELU, write next-layer xs (bf16)
      #pragma unroll
      for (int nt = 0; nt < 2; ++nt){
        int i = nt*16 + lm;
        if (i < 26){
          int rowb = (w*26 + i)*40;
          #pragma unroll
          for (int mt = 0; mt < 2; ++mt){
            f32x4 a = (mt == 0) ? (nt == 0 ? acc00 : acc01)
                                : (nt == 0 ? acc10 : acc11);
            int f0 = mt*16 + q*4;
            float v0 = a[0]*0.25f, v1 = a[1]*0.25f, v2 = a[2]*0.25f, v3 = a[3]*0.25f;
            v0 = (v0 > 0.f) ? v0 : expm1f(v0);
            v1 = (v1 > 0.f) ? v1 : expm1f(v1);
            v2 = (v2 > 0.f) ? v2 : expm1f(v2);
            v3 = (v3 > 0.f) ? v3 : expm1f(v3);
            if (f0 <= 20){
              uint2 uu; uu.x = pack2(v0, v1); uu.y = pack2(v2, v3);
              *(uint2*)&xs[rowb + f0] = uu;
            } else if (f0 == 24){
              *(u32*)&xs[rowb + 24] = pack2(v0, v1);
            }
          }
        }
      }
    }
  }
  __syncthreads();
  // store x_final (bf16, K padded to 704)
  for (int e = tid; e < 4*704; e += 256){
    int b = e/704, c = e%704;
    u16 v = 0;
    if (c < 676) v = xs[(b*26 + c/26)*40 + (c%26)];
    xf[(b0 + b)*704 + c] = v;
  }
}

// ---------------------------------------------------------------------------
// W1 -> bf16 W1^T [256][704] (zero-padded K)
// ---------------------------------------------------------------------------
__global__ __launch_bounds__(256) void w1cvt_kernel(const float* __restrict__ W1,
                                                    u16* __restrict__ w1t)
{
  int idx = blockIdx.x*256 + threadIdx.x;   // 704*256 total
  int k = idx >> 8, n = idx & 255;
  u16 v = 0;
  if (k < 676) v = f2bf(W1[k*256 + n]);
  w1t[n*704 + k] = v;
}

// ---------------------------------------------------------------------------
// MLP: out = leaky(xf @ W1 + b1, 0.2) @ W2 + b2.  BM=64, BN=256 (full),
// wave tile 64x64, fused W2 head via shfl_xor reduction.
// ---------------------------------------------------------------------------
__global__ __launch_bounds__(256) void mlp_kernel(
    const u16* __restrict__ xf, const u16* __restrict__ w1t,
    const float* __restrict__ b1, const float* __restrict__ w2,
    const float* __restrict__ b2, float* __restrict__ out)
{
  __shared__ u16   xtile[64*40];
  __shared__ u16   wtile[256*40];
  __shared__ float b1s[256];
  __shared__ float w2s[256*3];
  __shared__ float part[4*64*3];

  const int tid  = threadIdx.x;
  const int w    = tid >> 6;
  const int lane = tid & 63;
  const int q    = lane >> 4;
  const int lm   = lane & 15;
  const int m0   = blockIdx.x * 64;

  b1s[tid] = b1[tid];
  for (int e = tid; e < 768; e += 256) w2s[e] = w2[e];

  f32x4 acc[4][4];
  #pragma unroll
  for (int a = 0; a < 4; ++a)
    #pragma unroll
    for (int b = 0; b < 4; ++b) acc[a][b] = (f32x4){0.f,0.f,0.f,0.f};

  for (int kc = 0; kc < 22; ++kc){
    __syncthreads();
    {
      const int xr = tid >> 2, xc = (tid & 3)*8;
      uint4 xv = *(const uint4*)(xf + (m0 + xr)*704 + kc*32 + xc);
      *(uint4*)&xtile[xr*40 + xc] = xv;
      #pragma unroll
      for (int c = 0; c < 4; ++c){
        uint4 wv = *(const uint4*)(w1t + tid*704 + kc*32 + c*8);
        *(uint4*)&wtile[tid*40 + c*8] = wv;
      }
    }
    __syncthreads();
    s16x8 af[4], bf[4];
    #pragma unroll
    for (int mt = 0; mt < 4; ++mt) af[mt] = *(const s16x8*)&xtile[(mt*16 + lm)*40 + q*8];
    #pragma unroll
    for (int nt = 0; nt < 4; ++nt) bf[nt] = *(const s16x8*)&wtile[(w*64 + nt*16 + lm)*40 + q*8];
    #pragma unroll
    for (int mt = 0; mt < 4; ++mt)
      #pragma unroll
      for (int nt = 0; nt < 4; ++nt)
        acc[mt][nt] = MFMA16(af[mt], bf[nt], acc[mt][nt]);
  }

  // epilogue: +b1, leaky, @W2 partials, reduce over 16 lanes (cols)
  float b1l[4], w2l[4][3];
  #pragma unroll
  for (int nt = 0; nt < 4; ++nt){
    int col = w*64 + nt*16 + lm;
    b1l[nt] = b1s[col];
    w2l[nt][0] = w2s[col*3]; w2l[nt][1] = w2s[col*3+1]; w2l[nt][2] = w2s[col*3+2];
  }
  float po[4][4][3];
  #pragma unroll
  for (int mt = 0; mt < 4; ++mt)
    #pragma unroll
    for (int r = 0; r < 4; ++r){
      float s0 = 0.f, s1 = 0.f, s2 = 0.f;
      #pragma unroll
      for (int nt = 0; nt < 4; ++nt){
        float hv = acc[mt][nt][r] + b1l[nt];
        hv = (hv >= 0.f) ? hv : 0.2f*hv;
        s0 += hv*w2l[nt][0]; s1 += hv*w2l[nt][1]; s2 += hv*w2l[nt][2];
      }
      po[mt][r][0] = s0; po[mt][r][1] = s1; po[mt][r][2] = s2;
    }
  #pragma unroll
  for (int m = 1; m < 16; m <<= 1)
    #pragma unroll
    for (int mt = 0; mt < 4; ++mt)
      #pragma unroll
      for (int r = 0; r < 4; ++r)
        #pragma unroll
        for (int kk = 0; kk < 3; ++kk)
          po[mt][r][kk] += __shfl_xor(po[mt][r][kk], m);
  if (lm == 0){
    #pragma unroll
    for (int mt = 0; mt < 4; ++mt)
      #pragma unroll
      for (int r = 0; r < 4; ++r)
        #pragma unroll
        for (int kk = 0; kk < 3; ++kk)
          part[(w*64 + mt*16 + q*4 + r)*3 + kk] = po[mt][r][kk];
  }
  __syncthreads();
  if (tid < 192){
    int row = tid/3, kk = tid - row*3;
    float o = part[row*3 + kk] + part[192 + row*3 + kk]
            + part[384 + row*3 + kk] + part[576 + row*3 + kk] + b2[kk];
    out[(m0 + row)*3 + kk] = o;
  }
}

extern "C" void kernel_launch(void* const* d_in, const int* in_sizes, int n_in,
                              void* d_out, int out_size, void* d_ws, size_t ws_size,
                              hipStream_t stream)
{
  (void)in_sizes; (void)n_in; (void)out_size; (void)ws_size;
  const float* x     = (const float*)d_in[1];
  const float* W     = (const float*)d_in[2];
  const float* a_src = (const float*)d_in[3];
  const float* a_dst = (const float*)d_in[4];
  const float* W1    = (const float*)d_in[5];
  const float* b1    = (const float*)d_in[6];
  const float* W2    = (const float*)d_in[7];
  const float* b2    = (const float*)d_in[8];
  float* out = (float*)d_out;

  u16* xfinal = (u16*)d_ws;                  // [16384][704] bf16
  u16* w1t    = xfinal + 16384*704;          // [256][704]  bf16

  hipLaunchKernelGGL(w1cvt_kernel, dim3(704),  dim3(256), 0, stream, W1, w1t);
  hipLaunchKernelGGL(gat_kernel,   dim3(4096), dim3(256), 0, stream, x, W, a_src, a_dst, xfinal);
  hipLaunchKernelGGL(mlp_kernel,   dim3(256),  dim3(256), 0, stream, xfinal, w1t, b1, W2, b2, out);
}

// Round 3
// 243.076 us; speedup vs baseline: 1.3267x; 1.3267x over previous
//
#include <hip/hip_runtime.h>

typedef __attribute__((ext_vector_type(8))) short s16x8;
typedef __attribute__((ext_vector_type(4))) float f32x4;
typedef unsigned short u16;
typedef unsigned int   u32;

#define MFMA16(a,b,c) __builtin_amdgcn_mfma_f32_16x16x32_bf16((a),(b),(c),0,0,0)

__device__ __forceinline__ float bf2f(u16 u){
  u32 x = ((u32)u) << 16; float f; __builtin_memcpy(&f, &x, 4); return f;
}
__device__ __forceinline__ u16 f2bf(float f){
  u32 x; __builtin_memcpy(&x, &f, 4);
  x += 0x7FFFu + ((x >> 16) & 1u);   // round-to-nearest-even
  return (u16)(x >> 16);
}
#if defined(__has_builtin) && __has_builtin(__builtin_amdgcn_cvt_pk_bf16_f32)
__device__ __forceinline__ u32 pack2(float a, float b){
  return __builtin_bit_cast(u32, __builtin_amdgcn_cvt_pk_bf16_f32(a, b));
}
#else
__device__ __forceinline__ u32 pack2(float a, float b){
  return (u32)f2bf(a) | ((u32)f2bf(b) << 16);
}
#endif

// ---------------------------------------------------------------------------
// wprep: once-per-launch W preparation (was redundantly done by 4096 blocks).
// wp[l*4+h] is a [32 rows o][stride 40 f] bf16 tile:
//   rows 0..25 : W[l][h][f][o] transposed  (cols f, zero-padded f>=26)
//   row 26     : (W @ a_src)[f]    row 27 : (W @ a_dst)[f]
//   rows 28..31: 0
// ---------------------------------------------------------------------------
__global__ __launch_bounds__(256) void wprep_kernel(
    const float* __restrict__ W, const float* __restrict__ a_src,
    const float* __restrict__ a_dst, u16* __restrict__ wp)
{
  const int lh = blockIdx.x;             // 0..11 = l*4+h
  const float* Wlh = W + lh*676;         // [f][o]
  u16* dst = wp + lh*32*40;
  const int t = threadIdx.x;
  for (int e = t; e < 1280; e += 256) dst[e] = 0;
  __syncthreads();
  for (int e = t; e < 676; e += 256){ int f = e/26, o = e%26; dst[o*40 + f] = f2bf(Wlh[f*26 + o]); }
  if (t < 52){
    int sel = t/26, f = t%26;
    const float* av = (sel ? a_dst : a_src) + lh*26;
    float acc = 0.f;
    #pragma unroll
    for (int o = 0; o < 26; ++o) acc += Wlh[f*26 + o]*av[o];
    dst[(26 + sel)*40 + f] = f2bf(acc);
  }
}

// ---------------------------------------------------------------------------
// GAT kernel: 3 layers fused. One block = 4 batch elements, 256 threads.
// wave w = head w for matmul1; wave w = local batch bl=w for matmul2.
// LDS (bf16): xs [112 rows][40], hsT [4 h][32 o][108] (+16 tail).
// hsT padding (rows 28..31, cols 104..107, tail) zeroed once; data region is
// fully rewritten every layer. W fragments read from global wp (L1-resident).
// ---------------------------------------------------------------------------
__global__ __launch_bounds__(256) void gat_kernel(
    const float* __restrict__ x, const u16* __restrict__ wp,
    u16* __restrict__ xf)
{
  __shared__ u16 xs [112*40];
  __shared__ u16 hsT[4*32*108 + 16];

  const int tid  = threadIdx.x;
  const int w    = tid >> 6;
  const int lane = tid & 63;
  const int q    = lane >> 4;
  const int lm   = lane & 15;
  const int b0   = blockIdx.x * 4;

  // zero hsT padding once (never written afterwards)
  for (int e = tid; e < 1728; e += 256){            // rows (o&31)>=28, all cols
    int r = e/108, c = e%108; int h = r>>2, rr = 28 + (r&3);
    hsT[(h*32 + rr)*108 + c] = 0;
  }
  for (int e = tid; e < 448; e += 256){             // cols 104..107, rows 0..27
    int r = e>>2, c = 104 + (e&3); int h = r/28, rr = r%28;
    hsT[(h*32 + rr)*108 + c] = 0;
  }
  if (tid < 16) hsT[4*32*108 + tid] = 0;
  // zero xs padding: cols 26..39 (all rows), rows 104..111 (cols 0..25)
  for (int e = tid; e < 112*14; e += 256){ int r = e/14, c = 26 + e%14; xs[r*40 + c] = 0; }
  for (int e = tid; e < 8*26;  e += 256){ int r = 104 + e/26, c = e%26; xs[r*40 + c] = 0; }
  // load x (fp32 pairs -> packed bf16)
  for (int pp = tid; pp < 1352; pp += 256){
    int b = pp/338, r2 = pp%338, n = r2/13, p = r2%13;
    float2 v = *(const float2*)&x[(b0 + b)*676 + n*26 + 2*p];
    *(u32*)&xs[(b*26 + n)*40 + 2*p] = pack2(v.x, v.y);
  }

  for (int l = 0; l < 3; ++l){
    __syncthreads();

    // ---- matmul1: h_aug = x @ W_aug  (head = w, W frags from global) ----
    {
      s16x8 bfr0 = *(const s16x8*)&wp[((l*4 + w)*32      + lm)*40 + q*8];
      s16x8 bfr1 = *(const s16x8*)&wp[((l*4 + w)*32 + 16 + lm)*40 + q*8];
      #pragma unroll
      for (int t = 0; t < 7; ++t){
        s16x8 af = *(const s16x8*)&xs[(t*16 + lm)*40 + q*8];
        f32x4 z = {0.f,0.f,0.f,0.f};
        f32x4 d0 = MFMA16(af, bfr0, z);
        f32x4 d1 = MFMA16(af, bfr1, z);
        int gr0 = t*16 + q*4;
        if (gr0 < 104){
          { uint2 uu; uu.x = pack2(d0[0], d0[1]); uu.y = pack2(d0[2], d0[3]);
            *(uint2*)&hsT[(w*32 + lm)*108 + gr0] = uu; }
          if (lm < 12){
            uint2 uu; uu.x = pack2(d1[0], d1[1]); uu.y = pack2(d1[2], d1[3]);
            *(uint2*)&hsT[(w*32 + 16 + lm)*108 + gr0] = uu; }
        }
      }
    }
    __syncthreads();

    // ---- matmul2: out^T = h^T @ alpha^T, softmax built in-register (bl = w)
    {
      f32x4 acc00 = {0,0,0,0}, acc01 = acc00, acc10 = acc00, acc11 = acc00;
      const int j0 = q*8;
      #pragma unroll
      for (int h = 0; h < 4; ++h){
        s16x8 am0, am1;
        {
          int base = (h*32 + lm)*108 + w*26 + j0;
          uint4 uu = { *(const u32*)&hsT[base],   *(const u32*)&hsT[base+2],
                       *(const u32*)&hsT[base+4], *(const u32*)&hsT[base+6] };
          am0 = __builtin_bit_cast(s16x8, uu);
          base = (h*32 + 16 + lm)*108 + w*26 + j0;
          uint4 vv = { *(const u32*)&hsT[base],   *(const u32*)&hsT[base+2],
                       *(const u32*)&hsT[base+4], *(const u32*)&hsT[base+6] };
          am1 = __builtin_bit_cast(s16x8, vv);
        }
        float sd[8];
        {
          int base = (h*32 + 27)*108 + w*26 + j0;
          #pragma unroll
          for (int u = 0; u < 4; ++u){
            u32 v = *(const u32*)&hsT[base + 2*u];
            sd[2*u]   = bf2f((u16)(v & 0xFFFFu));
            sd[2*u+1] = bf2f((u16)(v >> 16));
          }
        }
        #pragma unroll
        for (int nt = 0; nt < 2; ++nt){
          int i = nt*16 + lm;
          float si = (i < 26) ? bf2f(hsT[(h*32 + 26)*108 + w*26 + i]) : 0.f;
          float p[8]; float loc = 0.f;
          #pragma unroll
          for (int jj = 0; jj < 8; ++jj){
            float e = si + sd[jj];
            e = (e >= 0.f) ? e : 0.2f*e;            // leaky_relu 0.2
            float pv = ((j0 + jj) < 26 && i < 26) ? __expf(e) : 0.f;
            p[jj] = pv; loc += pv;
          }
          float tot = loc;
          tot += __shfl_xor(tot, 16);
          tot += __shfl_xor(tot, 32);
          float rinv = (tot > 0.f) ? 1.f / tot : 0.f;
          uint4 bu = { pack2(p[0]*rinv, p[1]*rinv), pack2(p[2]*rinv, p[3]*rinv),
                       pack2(p[4]*rinv, p[5]*rinv), pack2(p[6]*rinv, p[7]*rinv) };
          s16x8 bfrag = __builtin_bit_cast(s16x8, bu);
          if (nt == 0){ acc00 = MFMA16(am0, bfrag, acc00);
                        acc10 = MFMA16(am1, bfrag, acc10); }
          else        { acc01 = MFMA16(am0, bfrag, acc01);
                        acc11 = MFMA16(am1, bfrag, acc11); }
        }
      }
      // epilogue: mean heads (x0.25), ELU, write next-layer xs (bf16)
      #pragma unroll
      for (int nt = 0; nt < 2; ++nt){
        int i = nt*16 + lm;
        if (i < 26){
          int rowb = (w*26 + i)*40;
          #pragma unroll
          for (int mt = 0; mt < 2; ++mt){
            f32x4 a = (mt == 0) ? (nt == 0 ? acc00 : acc01)
                                : (nt == 0 ? acc10 : acc11);
            int f0 = mt*16 + q*4;
            float v0 = a[0]*0.25f, v1 = a[1]*0.25f, v2 = a[2]*0.25f, v3 = a[3]*0.25f;
            v0 = (v0 > 0.f) ? v0 : (__expf(v0) - 1.f);
            v1 = (v1 > 0.f) ? v1 : (__expf(v1) - 1.f);
            v2 = (v2 > 0.f) ? v2 : (__expf(v2) - 1.f);
            v3 = (v3 > 0.f) ? v3 : (__expf(v3) - 1.f);
            if (f0 <= 20){
              uint2 uu; uu.x = pack2(v0, v1); uu.y = pack2(v2, v3);
              *(uint2*)&xs[rowb + f0] = uu;
            } else if (f0 == 24){
              *(u32*)&xs[rowb + 24] = pack2(v0, v1);
            }
          }
        }
      }
    }
  }
  __syncthreads();
  // store x_final (bf16, K padded to 704), u32-paired
  for (int pp = tid; pp < 1408; pp += 256){
    int b = pp/352, p = pp%352;
    u32 v = 0;
    if (p < 338){ int r2 = p/13, c = 2*(p%13); v = *(const u32*)&xs[(b*26 + r2)*40 + c]; }
    *(u32*)&xf[(b0 + b)*704 + 2*p] = v;
  }
}

// ---------------------------------------------------------------------------
// W1 -> bf16 W1^T [256][704] (zero-padded K)
// ---------------------------------------------------------------------------
__global__ __launch_bounds__(256) void w1cvt_kernel(const float* __restrict__ W1,
                                                    u16* __restrict__ w1t)
{
  int idx = blockIdx.x*256 + threadIdx.x;   // 704*256 total
  int k = idx >> 8, n = idx & 255;
  u16 v = 0;
  if (k < 676) v = f2bf(W1[k*256 + n]);
  w1t[n*704 + k] = v;
}

// ---------------------------------------------------------------------------
// MLP: out = leaky(xf @ W1 + b1, 0.2) @ W2 + b2.  BM=32 (512 blocks, 2/CU),
// BN=256, wave tile 32x64, fused W2 head via shfl_xor reduction.
// ---------------------------------------------------------------------------
__global__ __launch_bounds__(256) void mlp_kernel(
    const u16* __restrict__ xf, const u16* __restrict__ w1t,
    const float* __restrict__ b1, const float* __restrict__ w2,
    const float* __restrict__ b2, float* __restrict__ out)
{
  __shared__ u16   xtile[32*40];
  __shared__ u16   wtile[256*40];
  __shared__ float b1s[256];
  __shared__ float w2s[256*3];
  __shared__ float part[4*32*3];

  const int tid  = threadIdx.x;
  const int w    = tid >> 6;
  const int lane = tid & 63;
  const int q    = lane >> 4;
  const int lm   = lane & 15;
  const int m0   = blockIdx.x * 32;

  b1s[tid] = b1[tid];
  for (int e = tid; e < 768; e += 256) w2s[e] = w2[e];

  f32x4 acc[2][4];
  #pragma unroll
  for (int a = 0; a < 2; ++a)
    #pragma unroll
    for (int b = 0; b < 4; ++b) acc[a][b] = (f32x4){0.f,0.f,0.f,0.f};

  for (int kc = 0; kc < 22; ++kc){
    __syncthreads();
    {
      if (tid < 128){
        const int xr = tid >> 2, xc = (tid & 3)*8;
        uint4 xv = *(const uint4*)(xf + (m0 + xr)*704 + kc*32 + xc);
        *(uint4*)&xtile[xr*40 + xc] = xv;
      }
      #pragma unroll
      for (int c = 0; c < 4; ++c){
        uint4 wv = *(const uint4*)(w1t + tid*704 + kc*32 + c*8);
        *(uint4*)&wtile[tid*40 + c*8] = wv;
      }
    }
    __syncthreads();
    s16x8 af[2], bf[4];
    #pragma unroll
    for (int mt = 0; mt < 2; ++mt) af[mt] = *(const s16x8*)&xtile[(mt*16 + lm)*40 + q*8];
    #pragma unroll
    for (int nt = 0; nt < 4; ++nt) bf[nt] = *(const s16x8*)&wtile[(w*64 + nt*16 + lm)*40 + q*8];
    #pragma unroll
    for (int mt = 0; mt < 2; ++mt)
      #pragma unroll
      for (int nt = 0; nt < 4; ++nt)
        acc[mt][nt] = MFMA16(af[mt], bf[nt], acc[mt][nt]);
  }

  // epilogue: +b1, leaky, @W2 partials, reduce over 16 lanes (cols)
  float b1l[4], w2l[4][3];
  #pragma unroll
  for (int nt = 0; nt < 4; ++nt){
    int col = w*64 + nt*16 + lm;
    b1l[nt] = b1s[col];
    w2l[nt][0] = w2s[col*3]; w2l[nt][1] = w2s[col*3+1]; w2l[nt][2] = w2s[col*3+2];
  }
  float po[2][4][3];
  #pragma unroll
  for (int mt = 0; mt < 2; ++mt)
    #pragma unroll
    for (int r = 0; r < 4; ++r){
      float s0 = 0.f, s1 = 0.f, s2 = 0.f;
      #pragma unroll
      for (int nt = 0; nt < 4; ++nt){
        float hv = acc[mt][nt][r] + b1l[nt];
        hv = (hv >= 0.f) ? hv : 0.2f*hv;
        s0 += hv*w2l[nt][0]; s1 += hv*w2l[nt][1]; s2 += hv*w2l[nt][2];
      }
      po[mt][r][0] = s0; po[mt][r][1] = s1; po[mt][r][2] = s2;
    }
  #pragma unroll
  for (int m = 1; m < 16; m <<= 1)
    #pragma unroll
    for (int mt = 0; mt < 2; ++mt)
      #pragma unroll
      for (int r = 0; r < 4; ++r)
        #pragma unroll
        for (int kk = 0; kk < 3; ++kk)
          po[mt][r][kk] += __shfl_xor(po[mt][r][kk], m);
  if (lm == 0){
    #pragma unroll
    for (int mt = 0; mt < 2; ++mt)
      #pragma unroll
      for (int r = 0; r < 4; ++r)
        #pragma unroll
        for (int kk = 0; kk < 3; ++kk)
          part[w*96 + (mt*16 + q*4 + r)*3 + kk] = po[mt][r][kk];
  }
  __syncthreads();
  if (tid < 96){
    int row = tid/3, kk = tid - row*3;
    float o = part[row*3 + kk] + part[96 + row*3 + kk]
            + part[192 + row*3 + kk] + part[288 + row*3 + kk] + b2[kk];
    out[(m0 + row)*3 + kk] = o;
  }
}

extern "C" void kernel_launch(void* const* d_in, const int* in_sizes, int n_in,
                              void* d_out, int out_size, void* d_ws, size_t ws_size,
                              hipStream_t stream)
{
  (void)in_sizes; (void)n_in; (void)out_size; (void)ws_size;
  const float* x     = (const float*)d_in[1];
  const float* W     = (const float*)d_in[2];
  const float* a_src = (const float*)d_in[3];
  const float* a_dst = (const float*)d_in[4];
  const float* W1    = (const float*)d_in[5];
  const float* b1    = (const float*)d_in[6];
  const float* W2    = (const float*)d_in[7];
  const float* b2    = (const float*)d_in[8];
  float* out = (float*)d_out;

  u16* xfinal = (u16*)d_ws;                    // [16384][704] bf16
  u16* w1t    = xfinal + 16384*704;            // [256][704]  bf16
  u16* wp     = w1t    + 256*704;              // [12][32][40] bf16

  hipLaunchKernelGGL(wprep_kernel, dim3(12),   dim3(256), 0, stream, W, a_src, a_dst, wp);
  hipLaunchKernelGGL(w1cvt_kernel, dim3(704),  dim3(256), 0, stream, W1, w1t);
  hipLaunchKernelGGL(gat_kernel,   dim3(4096), dim3(256), 0, stream, x, wp, xfinal);
  hipLaunchKernelGGL(mlp_kernel,   dim3(512),  dim3(256), 0, stream, xfinal, w1t, b1, W2, b2, out);
}

// Round 4
// 237.377 us; speedup vs baseline: 1.3586x; 1.0240x over previous
//
#include <hip/hip_runtime.h>

typedef __attribute__((ext_vector_type(8))) short s16x8;
typedef __attribute__((ext_vector_type(4))) float f32x4;
typedef unsigned short u16;
typedef unsigned int   u32;

#define MFMA16(a,b,c) __builtin_amdgcn_mfma_f32_16x16x32_bf16((a),(b),(c),0,0,0)

__device__ __forceinline__ float bf2f(u16 u){
  u32 x = ((u32)u) << 16; float f; __builtin_memcpy(&f, &x, 4); return f;
}
__device__ __forceinline__ u16 f2bf(float f){
  u32 x; __builtin_memcpy(&x, &f, 4);
  x += 0x7FFFu + ((x >> 16) & 1u);   // round-to-nearest-even
  return (u16)(x >> 16);
}
#if defined(__has_builtin) && __has_builtin(__builtin_amdgcn_cvt_pk_bf16_f32)
__device__ __forceinline__ u32 pack2(float a, float b){
  return __builtin_bit_cast(u32, __builtin_amdgcn_cvt_pk_bf16_f32(a, b));
}
#else
__device__ __forceinline__ u32 pack2(float a, float b){
  return (u32)f2bf(a) | ((u32)f2bf(b) << 16);
}
#endif
#if defined(__has_builtin) && __has_builtin(__builtin_amdgcn_exp2f)
__device__ __forceinline__ float fexp2(float x){ return __builtin_amdgcn_exp2f(x); }
#else
extern "C" __device__ float __ocml_native_exp2_f32(float);
__device__ __forceinline__ float fexp2(float x){ return __ocml_native_exp2_f32(x); }
#endif

// ---------------------------------------------------------------------------
// wprep: once-per-launch W preparation.
// wp[l*4+h] is a [32 rows o][stride 40 f] bf16 tile:
//   rows 0..25 : W[l][h][f][o] transposed; row 26: W@a_src; row 27: W@a_dst;
//   rows 28..31 / cols >=26 : 0
// ---------------------------------------------------------------------------
__global__ __launch_bounds__(256) void wprep_kernel(
    const float* __restrict__ W, const float* __restrict__ a_src,
    const float* __restrict__ a_dst, u16* __restrict__ wp)
{
  const int lh = blockIdx.x;             // 0..11 = l*4+h
  const float* Wlh = W + lh*676;         // [f][o]
  u16* dst = wp + lh*32*40;
  const int t = threadIdx.x;
  for (int e = t; e < 1280; e += 256) dst[e] = 0;
  __syncthreads();
  for (int e = t; e < 676; e += 256){ int f = e/26, o = e%26; dst[o*40 + f] = f2bf(Wlh[f*26 + o]); }
  if (t < 52){
    int sel = t/26, f = t%26;
    const float* av = (sel ? a_dst : a_src) + lh*26;
    float acc = 0.f;
    #pragma unroll
    for (int o = 0; o < 26; ++o) acc += Wlh[f*26 + o]*av[o];
    dst[(26 + sel)*40 + f] = f2bf(acc);
  }
}

// ---------------------------------------------------------------------------
// GAT kernel: 3 layers fused. One block = 4 batch elements, 256 threads.
// wave w = head w for matmul1; wave w = local batch bl=w for matmul2.
// LDS (bf16): xs [112 rows][40], hsT [4 h][32 o][108] (+16 tail).
// Softmax in log2 domain: exp(leaky(e)) == exp2(leaky(e*log2e)) since
// leaky_relu is positively homogeneous. j>=26 masked once per h via -1e30 in
// sd2; i>=26 needs no mask (garbage stays in discarded MFMA B/D columns).
// ---------------------------------------------------------------------------
__global__ __launch_bounds__(256, 4) void gat_kernel(
    const float* __restrict__ x, const u16* __restrict__ wp,
    u16* __restrict__ xf)
{
  __shared__ u16 xs [112*40];
  __shared__ u16 hsT[4*32*108 + 16];

  const int tid  = threadIdx.x;
  const int w    = tid >> 6;
  const int lane = tid & 63;
  const int q    = lane >> 4;
  const int lm   = lane & 15;
  const int b0   = blockIdx.x * 4;
  const float L2E = 1.4426950408889634f;

  // zero hsT padding once (never written afterwards)
  for (int e = tid; e < 1728; e += 256){            // rows (o&31)>=28, all cols
    int r = e/108, c = e%108; int h = r>>2, rr = 28 + (r&3);
    hsT[(h*32 + rr)*108 + c] = 0;
  }
  for (int e = tid; e < 448; e += 256){             // cols 104..107, rows 0..27
    int r = e>>2, c = 104 + (e&3); int h = r/28, rr = r%28;
    hsT[(h*32 + rr)*108 + c] = 0;
  }
  if (tid < 16) hsT[4*32*108 + tid] = 0;
  // zero xs padding: cols 26..39 (all rows), rows 104..111 (cols 0..25)
  for (int e = tid; e < 112*14; e += 256){ int r = e/14, c = 26 + e%14; xs[r*40 + c] = 0; }
  for (int e = tid; e < 8*26;  e += 256){ int r = 104 + e/26, c = e%26; xs[r*40 + c] = 0; }
  // load x (fp32 pairs -> packed bf16)
  for (int pp = tid; pp < 1352; pp += 256){
    int b = pp/338, r2 = pp%338, n = r2/13, p = r2%13;
    float2 v = *(const float2*)&x[(b0 + b)*676 + n*26 + 2*p];
    *(u32*)&xs[(b*26 + n)*40 + 2*p] = pack2(v.x, v.y);
  }

  for (int l = 0; l < 3; ++l){
    __syncthreads();

    // ---- matmul1: h_aug = x @ W_aug  (head = w, W frags from global) ----
    {
      s16x8 bfr0 = *(const s16x8*)&wp[((l*4 + w)*32      + lm)*40 + q*8];
      s16x8 bfr1 = *(const s16x8*)&wp[((l*4 + w)*32 + 16 + lm)*40 + q*8];
      #pragma unroll
      for (int t = 0; t < 7; ++t){
        s16x8 af = *(const s16x8*)&xs[(t*16 + lm)*40 + q*8];
        f32x4 z = {0.f,0.f,0.f,0.f};
        f32x4 d0 = MFMA16(af, bfr0, z);
        f32x4 d1 = MFMA16(af, bfr1, z);
        int gr0 = t*16 + q*4;
        if (gr0 < 104){
          { uint2 uu; uu.x = pack2(d0[0], d0[1]); uu.y = pack2(d0[2], d0[3]);
            *(uint2*)&hsT[(w*32 + lm)*108 + gr0] = uu; }
          if (lm < 12){
            uint2 uu; uu.x = pack2(d1[0], d1[1]); uu.y = pack2(d1[2], d1[3]);
            *(uint2*)&hsT[(w*32 + 16 + lm)*108 + gr0] = uu; }
        }
      }
    }
    __syncthreads();

    // ---- matmul2: out^T = h^T @ alpha^T, softmax built in-register (bl = w)
    {
      f32x4 acc00 = {0,0,0,0}, acc01 = acc00, acc10 = acc00, acc11 = acc00;
      const int j0 = q*8;
      const int w26 = w*26;
      #pragma unroll
      for (int h = 0; h < 4; ++h){
        s16x8 am0, am1;
        {
          int base = (h*32 + lm)*108 + w26 + j0;
          uint4 uu = { *(const u32*)&hsT[base],   *(const u32*)&hsT[base+2],
                       *(const u32*)&hsT[base+4], *(const u32*)&hsT[base+6] };
          am0 = __builtin_bit_cast(s16x8, uu);
          base = (h*32 + 16 + lm)*108 + w26 + j0;
          uint4 vv = { *(const u32*)&hsT[base],   *(const u32*)&hsT[base+2],
                       *(const u32*)&hsT[base+4], *(const u32*)&hsT[base+6] };
          am1 = __builtin_bit_cast(s16x8, vv);
        }
        float sd2[8];
        {
          int base = (h*32 + 27)*108 + w26 + j0;
          #pragma unroll
          for (int u = 0; u < 4; ++u){
            u32 v = *(const u32*)&hsT[base + 2*u];
            sd2[2*u]   = bf2f((u16)(v & 0xFFFFu)) * L2E;
            sd2[2*u+1] = bf2f((u16)(v >> 16))     * L2E;
          }
          #pragma unroll
          for (int jj = 0; jj < 8; ++jj)
            if (j0 + jj >= 26) sd2[jj] = -1e30f;   // exp2 -> 0, kills j-pad
        }
        #pragma unroll
        for (int nt = 0; nt < 2; ++nt){
          int i = nt*16 + lm;
          float si2 = bf2f(hsT[(h*32 + 26)*108 + w26 + i]) * L2E;  // i>=26: junk, contained
          float p[8]; float loc = 0.f;
          #pragma unroll
          for (int jj = 0; jj < 8; ++jj){
            float e = si2 + sd2[jj];
            e = fmaxf(e, 0.2f*e);                  // leaky_relu (log2 domain)
            float pv = fexp2(e);
            p[jj] = pv; loc += pv;
          }
          float tot = loc;
          tot += __shfl_xor(tot, 16);
          tot += __shfl_xor(tot, 32);
          float rinv = __builtin_amdgcn_rcpf(tot);
          uint4 bu = { pack2(p[0]*rinv, p[1]*rinv), pack2(p[2]*rinv, p[3]*rinv),
                       pack2(p[4]*rinv, p[5]*rinv), pack2(p[6]*rinv, p[7]*rinv) };
          s16x8 bfrag = __builtin_bit_cast(s16x8, bu);
          if (nt == 0){ acc00 = MFMA16(am0, bfrag, acc00);
                        acc10 = MFMA16(am1, bfrag, acc10); }
          else        { acc01 = MFMA16(am0, bfrag, acc01);
                        acc11 = MFMA16(am1, bfrag, acc11); }
        }
      }
      // epilogue: mean heads (x0.25), ELU, write next-layer xs (bf16)
      #pragma unroll
      for (int nt = 0; nt < 2; ++nt){
        int i = nt*16 + lm;
        if (i < 26){
          int rowb = (w26 + i)*40;
          #pragma unroll
          for (int mt = 0; mt < 2; ++mt){
            f32x4 a = (mt == 0) ? (nt == 0 ? acc00 : acc01)
                                : (nt == 0 ? acc10 : acc11);
            int f0 = mt*16 + q*4;
            float v0 = a[0]*0.25f, v1 = a[1]*0.25f, v2 = a[2]*0.25f, v3 = a[3]*0.25f;
            v0 = (v0 > 0.f) ? v0 : (fexp2(v0*L2E) - 1.f);
            v1 = (v1 > 0.f) ? v1 : (fexp2(v1*L2E) - 1.f);
            v2 = (v2 > 0.f) ? v2 : (fexp2(v2*L2E) - 1.f);
            v3 = (v3 > 0.f) ? v3 : (fexp2(v3*L2E) - 1.f);
            if (f0 <= 20){
              uint2 uu; uu.x = pack2(v0, v1); uu.y = pack2(v2, v3);
              *(uint2*)&xs[rowb + f0] = uu;
            } else if (f0 == 24){
              *(u32*)&xs[rowb + 24] = pack2(v0, v1);
            }
          }
        }
      }
    }
  }
  __syncthreads();
  // store x_final (bf16, K padded to 704), u32-paired
  for (int pp = tid; pp < 1408; pp += 256){
    int b = pp/352, p = pp%352;
    u32 v = 0;
    if (p < 338){ int r2 = p/13, c = 2*(p%13); v = *(const u32*)&xs[(b*26 + r2)*40 + c]; }
    *(u32*)&xf[(b0 + b)*704 + 2*p] = v;
  }
}

// ---------------------------------------------------------------------------
// W1 -> bf16 W1^T [256][704] (zero-padded K)
// ---------------------------------------------------------------------------
__global__ __launch_bounds__(256) void w1cvt_kernel(const float* __restrict__ W1,
                                                    u16* __restrict__ w1t)
{
  int idx = blockIdx.x*256 + threadIdx.x;   // 704*256 total
  int k = idx >> 8, n = idx & 255;
  u16 v = 0;
  if (k < 676) v = f2bf(W1[k*256 + n]);
  w1t[n*704 + k] = v;
}

// ---------------------------------------------------------------------------
// MLP: out = leaky(xf @ W1 + b1, 0.2) @ W2 + b2.  BM=32, grid 512 (2/CU).
// Barrier-free, LDS-free K-loop: A and B fragments loaded straight from
// global into registers (16B/lane, aligned). w1t (360 KB) is L2-resident;
// xf streamed once from HBM. Fused W2 head via shfl_xor reduction.
// ---------------------------------------------------------------------------
__global__ __launch_bounds__(256, 2) void mlp_kernel(
    const u16* __restrict__ xf, const u16* __restrict__ w1t,
    const float* __restrict__ b1, const float* __restrict__ w2,
    const float* __restrict__ b2, float* __restrict__ out)
{
  __shared__ float b1s[256];
  __shared__ float w2s[256*3];
  __shared__ float part[4*32*3];

  const int tid  = threadIdx.x;
  const int w    = tid >> 6;
  const int lane = tid & 63;
  const int q    = lane >> 4;
  const int lm   = lane & 15;
  const int m0   = blockIdx.x * 32;

  b1s[tid] = b1[tid];
  for (int e = tid; e < 768; e += 256) w2s[e] = w2[e];

  f32x4 acc[2][4];
  #pragma unroll
  for (int a = 0; a < 2; ++a)
    #pragma unroll
    for (int b = 0; b < 4; ++b) acc[a][b] = (f32x4){0.f,0.f,0.f,0.f};

  const u16* arow0 = xf + (m0 + lm)*704 + q*8;
  const u16* arow1 = arow0 + 16*704;
  const u16* brow0 = w1t + (w*64      + lm)*704 + q*8;
  const u16* brow1 = brow0 + 16*704;
  const u16* brow2 = brow0 + 32*704;
  const u16* brow3 = brow0 + 48*704;

  #pragma unroll
  for (int kc = 0; kc < 22; ++kc){
    const int ko = kc*32;
    s16x8 a0 = *(const s16x8*)(arow0 + ko);
    s16x8 a1 = *(const s16x8*)(arow1 + ko);
    s16x8 f0 = *(const s16x8*)(brow0 + ko);
    s16x8 f1 = *(const s16x8*)(brow1 + ko);
    s16x8 f2 = *(const s16x8*)(brow2 + ko);
    s16x8 f3 = *(const s16x8*)(brow3 + ko);
    acc[0][0] = MFMA16(a0, f0, acc[0][0]);
    acc[0][1] = MFMA16(a0, f1, acc[0][1]);
    acc[0][2] = MFMA16(a0, f2, acc[0][2]);
    acc[0][3] = MFMA16(a0, f3, acc[0][3]);
    acc[1][0] = MFMA16(a1, f0, acc[1][0]);
    acc[1][1] = MFMA16(a1, f1, acc[1][1]);
    acc[1][2] = MFMA16(a1, f2, acc[1][2]);
    acc[1][3] = MFMA16(a1, f3, acc[1][3]);
  }

  // epilogue: +b1, leaky, @W2 partials, reduce over 16 lanes (cols)
  float b1l[4], w2l[4][3];
  #pragma unroll
  for (int nt = 0; nt < 4; ++nt){
    int col = w*64 + nt*16 + lm;
    b1l[nt] = b1s[col];
    w2l[nt][0] = w2s[col*3]; w2l[nt][1] = w2s[col*3+1]; w2l[nt][2] = w2s[col*3+2];
  }
  float po[2][4][3];
  #pragma unroll
  for (int mt = 0; mt < 2; ++mt)
    #pragma unroll
    for (int r = 0; r < 4; ++r){
      float s0 = 0.f, s1 = 0.f, s2 = 0.f;
      #pragma unroll
      for (int nt = 0; nt < 4; ++nt){
        float hv = acc[mt][nt][r] + b1l[nt];
        hv = (hv >= 0.f) ? hv : 0.2f*hv;
        s0 += hv*w2l[nt][0]; s1 += hv*w2l[nt][1]; s2 += hv*w2l[nt][2];
      }
      po[mt][r][0] = s0; po[mt][r][1] = s1; po[mt][r][2] = s2;
    }
  #pragma unroll
  for (int m = 1; m < 16; m <<= 1)
    #pragma unroll
    for (int mt = 0; mt < 2; ++mt)
      #pragma unroll
      for (int r = 0; r < 4; ++r)
        #pragma unroll
        for (int kk = 0; kk < 3; ++kk)
          po[mt][r][kk] += __shfl_xor(po[mt][r][kk], m);
  if (lm == 0){
    #pragma unroll
    for (int mt = 0; mt < 2; ++mt)
      #pragma unroll
      for (int r = 0; r < 4; ++r)
        #pragma unroll
        for (int kk = 0; kk < 3; ++kk)
          part[w*96 + (mt*16 + q*4 + r)*3 + kk] = po[mt][r][kk];
  }
  __syncthreads();
  if (tid < 96){
    int row = tid/3, kk = tid - row*3;
    float o = part[row*3 + kk] + part[96 + row*3 + kk]
            + part[192 + row*3 + kk] + part[288 + row*3 + kk] + b2[kk];
    out[(m0 + row)*3 + kk] = o;
  }
}

extern "C" void kernel_launch(void* const* d_in, const int* in_sizes, int n_in,
                              void* d_out, int out_size, void* d_ws, size_t ws_size,
                              hipStream_t stream)
{
  (void)in_sizes; (void)n_in; (void)out_size; (void)ws_size;
  const float* x     = (const float*)d_in[1];
  const float* W     = (const float*)d_in[2];
  const float* a_src = (const float*)d_in[3];
  const float* a_dst = (const float*)d_in[4];
  const float* W1    = (const float*)d_in[5];
  const float* b1    = (const float*)d_in[6];
  const float* W2    = (const float*)d_in[7];
  const float* b2    = (const float*)d_in[8];
  float* out = (float*)d_out;

  u16* xfinal = (u16*)d_ws;                    // [16384][704] bf16
  u16* w1t    = xfinal + 16384*704;            // [256][704]  bf16
  u16* wp     = w1t    + 256*704;              // [12][32][40] bf16

  hipLaunchKernelGGL(wprep_kernel, dim3(12),   dim3(256), 0, stream, W, a_src, a_dst, wp);
  hipLaunchKernelGGL(w1cvt_kernel, dim3(704),  dim3(256), 0, stream, W1, w1t);
  hipLaunchKernelGGL(gat_kernel,   dim3(4096), dim3(256), 0, stream, x, wp, xfinal);
  hipLaunchKernelGGL(mlp_kernel,   dim3(512),  dim3(256), 0, stream, xfinal, w1t, b1, W2, b2, out);
}

// Round 5
// 224.007 us; speedup vs baseline: 1.4397x; 1.0597x over previous
//
#include <hip/hip_runtime.h>

typedef __attribute__((ext_vector_type(8))) short s16x8;
typedef __attribute__((ext_vector_type(4))) float f32x4;
typedef unsigned short u16;
typedef unsigned int   u32;

#define MFMA16(a,b,c) __builtin_amdgcn_mfma_f32_16x16x32_bf16((a),(b),(c),0,0,0)

__device__ __forceinline__ float bf2f(u16 u){
  u32 x = ((u32)u) << 16; float f; __builtin_memcpy(&f, &x, 4); return f;
}
__device__ __forceinline__ u16 f2bf(float f){
  u32 x; __builtin_memcpy(&x, &f, 4);
  x += 0x7FFFu + ((x >> 16) & 1u);   // round-to-nearest-even
  return (u16)(x >> 16);
}
#if defined(__has_builtin) && __has_builtin(__builtin_amdgcn_cvt_pk_bf16_f32)
__device__ __forceinline__ u32 pack2(float a, float b){
  return __builtin_bit_cast(u32, __builtin_amdgcn_cvt_pk_bf16_f32(a, b));
}
#else
__device__ __forceinline__ u32 pack2(float a, float b){
  return (u32)f2bf(a) | ((u32)f2bf(b) << 16);
}
#endif
#if defined(__has_builtin) && __has_builtin(__builtin_amdgcn_exp2f)
__device__ __forceinline__ float fexp2(float x){ return __builtin_amdgcn_exp2f(x); }
#else
extern "C" __device__ float __ocml_native_exp2_f32(float);
__device__ __forceinline__ float fexp2(float x){ return __ocml_native_exp2_f32(x); }
#endif

// Swizzled fragment layouts (MFMA 16x16x32 operand order):
//   xf_swz : [mtile=1024][kc=22][lane=64][8]  A[m=lane&15][k=kc*32+(lane>>4)*8+j]
//   w1_swz : [ntile=16]  [kc=22][lane=64][8]  B[k=kc*32+(lane>>4)*8+j][n=ntile*16+(lane&15)]
// -> every mlp fragment load is 64 lanes x contiguous 16B = 1 coalesced KB.

// ---------------------------------------------------------------------------
// wprep: once-per-launch W preparation.
// wp[l*4+h] is a [32 rows o][stride 40 f] bf16 tile:
//   rows 0..25 : W[l][h][f][o] transposed; row 26: W@a_src; row 27: W@a_dst;
//   rows 28..31 / cols >=26 : 0
// ---------------------------------------------------------------------------
__global__ __launch_bounds__(256) void wprep_kernel(
    const float* __restrict__ W, const float* __restrict__ a_src,
    const float* __restrict__ a_dst, u16* __restrict__ wp)
{
  const int lh = blockIdx.x;             // 0..11 = l*4+h
  const float* Wlh = W + lh*676;         // [f][o]
  u16* dst = wp + lh*32*40;
  const int t = threadIdx.x;
  for (int e = t; e < 1280; e += 256) dst[e] = 0;
  __syncthreads();
  for (int e = t; e < 676; e += 256){ int f = e/26, o = e%26; dst[o*40 + f] = f2bf(Wlh[f*26 + o]); }
  if (t < 52){
    int sel = t/26, f = t%26;
    const float* av = (sel ? a_dst : a_src) + lh*26;
    float acc = 0.f;
    #pragma unroll
    for (int o = 0; o < 26; ++o) acc += Wlh[f*26 + o]*av[o];
    dst[(26 + sel)*40 + f] = f2bf(acc);
  }
}

// ---------------------------------------------------------------------------
// GAT kernel: 3 layers fused. One block = 4 batch elements, 256 threads.
// (unchanged from round 4 except the final xf store writes the swizzled
// A-fragment layout consumed by mlp.)
// ---------------------------------------------------------------------------
__global__ __launch_bounds__(256, 4) void gat_kernel(
    const float* __restrict__ x, const u16* __restrict__ wp,
    u16* __restrict__ xf)
{
  __shared__ u16 xs [112*40];
  __shared__ u16 hsT[4*32*108 + 16];

  const int tid  = threadIdx.x;
  const int w    = tid >> 6;
  const int lane = tid & 63;
  const int q    = lane >> 4;
  const int lm   = lane & 15;
  const int b0   = blockIdx.x * 4;
  const float L2E = 1.4426950408889634f;

  // zero hsT padding once (never written afterwards)
  for (int e = tid; e < 1728; e += 256){            // rows (o&31)>=28, all cols
    int r = e/108, c = e%108; int h = r>>2, rr = 28 + (r&3);
    hsT[(h*32 + rr)*108 + c] = 0;
  }
  for (int e = tid; e < 448; e += 256){             // cols 104..107, rows 0..27
    int r = e>>2, c = 104 + (e&3); int h = r/28, rr = r%28;
    hsT[(h*32 + rr)*108 + c] = 0;
  }
  if (tid < 16) hsT[4*32*108 + tid] = 0;
  // zero xs padding: cols 26..39 (all rows), rows 104..111 (cols 0..25)
  for (int e = tid; e < 112*14; e += 256){ int r = e/14, c = 26 + e%14; xs[r*40 + c] = 0; }
  for (int e = tid; e < 8*26;  e += 256){ int r = 104 + e/26, c = e%26; xs[r*40 + c] = 0; }
  // load x (fp32 pairs -> packed bf16)
  for (int pp = tid; pp < 1352; pp += 256){
    int b = pp/338, r2 = pp%338, n = r2/13, p = r2%13;
    float2 v = *(const float2*)&x[(b0 + b)*676 + n*26 + 2*p];
    *(u32*)&xs[(b*26 + n)*40 + 2*p] = pack2(v.x, v.y);
  }

  for (int l = 0; l < 3; ++l){
    __syncthreads();

    // ---- matmul1: h_aug = x @ W_aug  (head = w, W frags from global) ----
    {
      s16x8 bfr0 = *(const s16x8*)&wp[((l*4 + w)*32      + lm)*40 + q*8];
      s16x8 bfr1 = *(const s16x8*)&wp[((l*4 + w)*32 + 16 + lm)*40 + q*8];
      #pragma unroll
      for (int t = 0; t < 7; ++t){
        s16x8 af = *(const s16x8*)&xs[(t*16 + lm)*40 + q*8];
        f32x4 z = {0.f,0.f,0.f,0.f};
        f32x4 d0 = MFMA16(af, bfr0, z);
        f32x4 d1 = MFMA16(af, bfr1, z);
        int gr0 = t*16 + q*4;
        if (gr0 < 104){
          { uint2 uu; uu.x = pack2(d0[0], d0[1]); uu.y = pack2(d0[2], d0[3]);
            *(uint2*)&hsT[(w*32 + lm)*108 + gr0] = uu; }
          if (lm < 12){
            uint2 uu; uu.x = pack2(d1[0], d1[1]); uu.y = pack2(d1[2], d1[3]);
            *(uint2*)&hsT[(w*32 + 16 + lm)*108 + gr0] = uu; }
        }
      }
    }
    __syncthreads();

    // ---- matmul2: out^T = h^T @ alpha^T, softmax built in-register (bl = w)
    {
      f32x4 acc00 = {0,0,0,0}, acc01 = acc00, acc10 = acc00, acc11 = acc00;
      const int j0 = q*8;
      const int w26 = w*26;
      #pragma unroll
      for (int h = 0; h < 4; ++h){
        s16x8 am0, am1;
        {
          int base = (h*32 + lm)*108 + w26 + j0;
          uint4 uu = { *(const u32*)&hsT[base],   *(const u32*)&hsT[base+2],
                       *(const u32*)&hsT[base+4], *(const u32*)&hsT[base+6] };
          am0 = __builtin_bit_cast(s16x8, uu);
          base = (h*32 + 16 + lm)*108 + w26 + j0;
          uint4 vv = { *(const u32*)&hsT[base],   *(const u32*)&hsT[base+2],
                       *(const u32*)&hsT[base+4], *(const u32*)&hsT[base+6] };
          am1 = __builtin_bit_cast(s16x8, vv);
        }
        float sd2[8];
        {
          int base = (h*32 + 27)*108 + w26 + j0;
          #pragma unroll
          for (int u = 0; u < 4; ++u){
            u32 v = *(const u32*)&hsT[base + 2*u];
            sd2[2*u]   = bf2f((u16)(v & 0xFFFFu)) * L2E;
            sd2[2*u+1] = bf2f((u16)(v >> 16))     * L2E;
          }
          #pragma unroll
          for (int jj = 0; jj < 8; ++jj)
            if (j0 + jj >= 26) sd2[jj] = -1e30f;   // exp2 -> 0, kills j-pad
        }
        #pragma unroll
        for (int nt = 0; nt < 2; ++nt){
          int i = nt*16 + lm;
          float si2 = bf2f(hsT[(h*32 + 26)*108 + w26 + i]) * L2E;  // i>=26: junk, contained
          float p[8]; float loc = 0.f;
          #pragma unroll
          for (int jj = 0; jj < 8; ++jj){
            float e = si2 + sd2[jj];
            e = fmaxf(e, 0.2f*e);                  // leaky_relu (log2 domain)
            float pv = fexp2(e);
            p[jj] = pv; loc += pv;
          }
          float tot = loc;
          tot += __shfl_xor(tot, 16);
          tot += __shfl_xor(tot, 32);
          float rinv = __builtin_amdgcn_rcpf(tot);
          uint4 bu = { pack2(p[0]*rinv, p[1]*rinv), pack2(p[2]*rinv, p[3]*rinv),
                       pack2(p[4]*rinv, p[5]*rinv), pack2(p[6]*rinv, p[7]*rinv) };
          s16x8 bfrag = __builtin_bit_cast(s16x8, bu);
          if (nt == 0){ acc00 = MFMA16(am0, bfrag, acc00);
                        acc10 = MFMA16(am1, bfrag, acc10); }
          else        { acc01 = MFMA16(am0, bfrag, acc01);
                        acc11 = MFMA16(am1, bfrag, acc11); }
        }
      }
      // epilogue: mean heads (x0.25), ELU, write next-layer xs (bf16)
      #pragma unroll
      for (int nt = 0; nt < 2; ++nt){
        int i = nt*16 + lm;
        if (i < 26){
          int rowb = (w26 + i)*40;
          #pragma unroll
          for (int mt = 0; mt < 2; ++mt){
            f32x4 a = (mt == 0) ? (nt == 0 ? acc00 : acc01)
                                : (nt == 0 ? acc10 : acc11);
            int f0 = mt*16 + q*4;
            float v0 = a[0]*0.25f, v1 = a[1]*0.25f, v2 = a[2]*0.25f, v3 = a[3]*0.25f;
            v0 = (v0 > 0.f) ? v0 : (fexp2(v0*L2E) - 1.f);
            v1 = (v1 > 0.f) ? v1 : (fexp2(v1*L2E) - 1.f);
            v2 = (v2 > 0.f) ? v2 : (fexp2(v2*L2E) - 1.f);
            v3 = (v3 > 0.f) ? v3 : (fexp2(v3*L2E) - 1.f);
            if (f0 <= 20){
              uint2 uu; uu.x = pack2(v0, v1); uu.y = pack2(v2, v3);
              *(uint2*)&xs[rowb + f0] = uu;
            } else if (f0 == 24){
              *(u32*)&xs[rowb + 24] = pack2(v0, v1);
            }
          }
        }
      }
    }
  }
  __syncthreads();
  // store x_final into swizzled A-fragment layout (u32-paired, zero K-pad)
  {
    const int mtile = b0 >> 4;
    u16* dstb = xf + (size_t)mtile*22*64*8;
    for (int pp = tid; pp < 1408; pp += 256){
      int b = pp/352, p = pp%352;           // p = k/2, k = 2p
      u32 v = 0;
      if (p < 338){ int r2 = p/13, c = 2*(p%13); v = *(const u32*)&xs[(b*26 + r2)*40 + c]; }
      int k = 2*p, kc = k >> 5, q16 = (k >> 3) & 3, j = k & 7;
      int lrow = (b0 & 15) + b;
      *(u32*)&dstb[((kc*64 + q16*16 + lrow) << 3) + j] = v;
    }
  }
}

// ---------------------------------------------------------------------------
// W1 -> bf16 swizzled B-fragment layout w1_swz[ntile=16][kc=22][lane=64][8].
// grid 352 (one k-pair per block), 256 threads = n. Reads coalesced over n.
// ---------------------------------------------------------------------------
__global__ __launch_bounds__(256) void w1cvt_kernel(const float* __restrict__ W1,
                                                    u16* __restrict__ w1t)
{
  const int k = blockIdx.x * 2;            // 0..702 even
  const int n = threadIdx.x;
  float v0 = 0.f, v1 = 0.f;
  if (k < 676)     v0 = W1[(size_t)k*256 + n];
  if (k + 1 < 676) v1 = W1[(size_t)(k+1)*256 + n];
  const int ntile = n >> 4, lm = n & 15;
  const int kc = k >> 5, q16 = (k >> 3) & 3, j = k & 7;
  u16* dst = w1t + ((((size_t)ntile*22 + kc)*64 + q16*16 + lm) << 3) + j;
  *(u32*)dst = pack2(v0, v1);
}

// ---------------------------------------------------------------------------
// MLP: out = leaky(xf @ W1 + b1, 0.2) @ W2 + b2.  BM=64, grid 256 (1/CU).
// Barrier-free, LDS-free K-loop; all fragments loaded coalesced (1KB/wave)
// from the swizzled layouts. Fused W2 head via shfl_xor reduction.
// ---------------------------------------------------------------------------
__global__ __launch_bounds__(256, 1) void mlp_kernel(
    const u16* __restrict__ xf, const u16* __restrict__ w1t,
    const float* __restrict__ b1, const float* __restrict__ w2,
    const float* __restrict__ b2, float* __restrict__ out)
{
  __shared__ float b1s[256];
  __shared__ float w2s[256*3];
  __shared__ float part[4*64*3];

  const int tid  = threadIdx.x;
  const int w    = tid >> 6;
  const int lane = tid & 63;
  const int q    = lane >> 4;
  const int lm   = lane & 15;
  const int m0   = blockIdx.x * 64;
  const int mt0  = blockIdx.x * 4;         // first mtile

  b1s[tid] = b1[tid];
  for (int e = tid; e < 768; e += 256) w2s[e] = w2[e];

  f32x4 acc[4][4];
  #pragma unroll
  for (int a = 0; a < 4; ++a)
    #pragma unroll
    for (int b = 0; b < 4; ++b) acc[a][b] = (f32x4){0.f,0.f,0.f,0.f};

  // base pointers: A mtiles mt0..mt0+3 ; B ntiles w*4..w*4+3
  const u16* abase = xf  + ((size_t)mt0*22*64 + lane) * 8;
  const u16* bbase = w1t + (((size_t)w*4)*22*64 + lane) * 8;

  #pragma unroll
  for (int kc = 0; kc < 22; ++kc){
    s16x8 af[4], bf[4];
    #pragma unroll
    for (int mt = 0; mt < 4; ++mt)
      af[mt] = *(const s16x8*)(abase + ((size_t)(mt*22 + kc)*64)*8);
    #pragma unroll
    for (int nt = 0; nt < 4; ++nt)
      bf[nt] = *(const s16x8*)(bbase + ((size_t)(nt*22 + kc)*64)*8);
    #pragma unroll
    for (int mt = 0; mt < 4; ++mt)
      #pragma unroll
      for (int nt = 0; nt < 4; ++nt)
        acc[mt][nt] = MFMA16(af[mt], bf[nt], acc[mt][nt]);
  }

  // epilogue: +b1, leaky, @W2 partials, reduce over 16 lanes (cols)
  float b1l[4], w2l[4][3];
  #pragma unroll
  for (int nt = 0; nt < 4; ++nt){
    int col = w*64 + nt*16 + lm;
    b1l[nt] = b1s[col];
    w2l[nt][0] = w2s[col*3]; w2l[nt][1] = w2s[col*3+1]; w2l[nt][2] = w2s[col*3+2];
  }
  float po[4][4][3];
  #pragma unroll
  for (int mt = 0; mt < 4; ++mt)
    #pragma unroll
    for (int r = 0; r < 4; ++r){
      float s0 = 0.f, s1 = 0.f, s2 = 0.f;
      #pragma unroll
      for (int nt = 0; nt < 4; ++nt){
        float hv = acc[mt][nt][r] + b1l[nt];
        hv = (hv >= 0.f) ? hv : 0.2f*hv;
        s0 += hv*w2l[nt][0]; s1 += hv*w2l[nt][1]; s2 += hv*w2l[nt][2];
      }
      po[mt][r][0] = s0; po[mt][r][1] = s1; po[mt][r][2] = s2;
    }
  #pragma unroll
  for (int m = 1; m < 16; m <<= 1)
    #pragma unroll
    for (int mt = 0; mt < 4; ++mt)
      #pragma unroll
      for (int r = 0; r < 4; ++r)
        #pragma unroll
        for (int kk = 0; kk < 3; ++kk)
          po[mt][r][kk] += __shfl_xor(po[mt][r][kk], m);
  if (lm == 0){
    #pragma unroll
    for (int mt = 0; mt < 4; ++mt)
      #pragma unroll
      for (int r = 0; r < 4; ++r)
        #pragma unroll
        for (int kk = 0; kk < 3; ++kk)
          part[(w*64 + mt*16 + q*4 + r)*3 + kk] = po[mt][r][kk];
  }
  __syncthreads();
  if (tid < 192){
    int row = tid/3, kk = tid - row*3;
    float o = part[row*3 + kk] + part[192 + row*3 + kk]
            + part[384 + row*3 + kk] + part[576 + row*3 + kk] + b2[kk];
    out[(m0 + row)*3 + kk] = o;
  }
}

extern "C" void kernel_launch(void* const* d_in, const int* in_sizes, int n_in,
                              void* d_out, int out_size, void* d_ws, size_t ws_size,
                              hipStream_t stream)
{
  (void)in_sizes; (void)n_in; (void)out_size; (void)ws_size;
  const float* x     = (const float*)d_in[1];
  const float* W     = (const float*)d_in[2];
  const float* a_src = (const float*)d_in[3];
  const float* a_dst = (const float*)d_in[4];
  const float* W1    = (const float*)d_in[5];
  const float* b1    = (const float*)d_in[6];
  const float* W2    = (const float*)d_in[7];
  const float* b2    = (const float*)d_in[8];
  float* out = (float*)d_out;

  u16* xfinal = (u16*)d_ws;                    // [1024][22][64][8] bf16 (swz)
  u16* w1t    = xfinal + (size_t)16384*704;    // [16][22][64][8]   bf16 (swz)
  u16* wp     = w1t    + 256*704;              // [12][32][40]      bf16

  hipLaunchKernelGGL(wprep_kernel, dim3(12),   dim3(256), 0, stream, W, a_src, a_dst, wp);
  hipLaunchKernelGGL(w1cvt_kernel, dim3(352),  dim3(256), 0, stream, W1, w1t);
  hipLaunchKernelGGL(gat_kernel,   dim3(4096), dim3(256), 0, stream, x, wp, xfinal);
  hipLaunchKernelGGL(mlp_kernel,   dim3(256),  dim3(256), 0, stream, xfinal, w1t, b1, W2, b2, out);
}

// Round 6
// 220.756 us; speedup vs baseline: 1.4609x; 1.0147x over previous
//
#include <hip/hip_runtime.h>

typedef __attribute__((ext_vector_type(8))) short s16x8;
typedef __attribute__((ext_vector_type(4))) float f32x4;
typedef unsigned short u16;
typedef unsigned int   u32;

#define MFMA16(a,b,c) __builtin_amdgcn_mfma_f32_16x16x32_bf16((a),(b),(c),0,0,0)

__device__ __forceinline__ float bf2f(u16 u){
  u32 x = ((u32)u) << 16; float f; __builtin_memcpy(&f, &x, 4); return f;
}
__device__ __forceinline__ u16 f2bf(float f){
  u32 x; __builtin_memcpy(&x, &f, 4);
  x += 0x7FFFu + ((x >> 16) & 1u);   // round-to-nearest-even
  return (u16)(x >> 16);
}
#if defined(__has_builtin) && __has_builtin(__builtin_amdgcn_cvt_pk_bf16_f32)
__device__ __forceinline__ u32 pack2(float a, float b){
  return __builtin_bit_cast(u32, __builtin_amdgcn_cvt_pk_bf16_f32(a, b));
}
#else
__device__ __forceinline__ u32 pack2(float a, float b){
  return (u32)f2bf(a) | ((u32)f2bf(b) << 16);
}
#endif
#if defined(__has_builtin) && __has_builtin(__builtin_amdgcn_exp2f)
__device__ __forceinline__ float fexp2(float x){ return __builtin_amdgcn_exp2f(x); }
#else
extern "C" __device__ float __ocml_native_exp2_f32(float);
__device__ __forceinline__ float fexp2(float x){ return __ocml_native_exp2_f32(x); }
#endif

// Swizzled fragment layouts (MFMA 16x16x32 operand order):
//   xf_swz : [mtile=1024][kc=22][lane=64][8]  A[m=lane&15][k=kc*32+(lane>>4)*8+j]
//   w1_swz : [ntile=16]  [kc=22][lane=64][8]  B[k=kc*32+(lane>>4)*8+j][n=ntile*16+(lane&15)]
// -> every mlp fragment load is 64 lanes x contiguous 16B = 1 coalesced KB.

// ---------------------------------------------------------------------------
// wprep: once-per-launch W preparation.
// wp[l*4+h] is a [32 rows o][stride 40 f] bf16 tile:
//   rows 0..25 : W[l][h][f][o] transposed; row 26: W@a_src; row 27: W@a_dst;
//   rows 28..31 / cols >=26 : 0
// ---------------------------------------------------------------------------
__global__ __launch_bounds__(256) void wprep_kernel(
    const float* __restrict__ W, const float* __restrict__ a_src,
    const float* __restrict__ a_dst, u16* __restrict__ wp)
{
  const int lh = blockIdx.x;             // 0..11 = l*4+h
  const float* Wlh = W + lh*676;         // [f][o]
  u16* dst = wp + lh*32*40;
  const int t = threadIdx.x;
  for (int e = t; e < 1280; e += 256) dst[e] = 0;
  __syncthreads();
  for (int e = t; e < 676; e += 256){ int f = e/26, o = e%26; dst[o*40 + f] = f2bf(Wlh[f*26 + o]); }
  if (t < 52){
    int sel = t/26, f = t%26;
    const float* av = (sel ? a_dst : a_src) + lh*26;
    float acc = 0.f;
    #pragma unroll
    for (int o = 0; o < 26; ++o) acc += Wlh[f*26 + o]*av[o];
    dst[(26 + sel)*40 + f] = f2bf(acc);
  }
}

// ---------------------------------------------------------------------------
// GAT kernel: 3 layers fused. One block = 4 batch elements, 256 threads.
// (round-4 body; final xf store rewritten destination-linear so each
// 16-thread group writes one contiguous 64B chunk of the swizzled layout.)
// ---------------------------------------------------------------------------
__global__ __launch_bounds__(256, 4) void gat_kernel(
    const float* __restrict__ x, const u16* __restrict__ wp,
    u16* __restrict__ xf)
{
  __shared__ u16 xs [112*40];
  __shared__ u16 hsT[4*32*108 + 16];

  const int tid  = threadIdx.x;
  const int w    = tid >> 6;
  const int lane = tid & 63;
  const int q    = lane >> 4;
  const int lm   = lane & 15;
  const int b0   = blockIdx.x * 4;
  const float L2E = 1.4426950408889634f;

  // zero hsT padding once (never written afterwards)
  for (int e = tid; e < 1728; e += 256){            // rows (o&31)>=28, all cols
    int r = e/108, c = e%108; int h = r>>2, rr = 28 + (r&3);
    hsT[(h*32 + rr)*108 + c] = 0;
  }
  for (int e = tid; e < 448; e += 256){             // cols 104..107, rows 0..27
    int r = e>>2, c = 104 + (e&3); int h = r/28, rr = r%28;
    hsT[(h*32 + rr)*108 + c] = 0;
  }
  if (tid < 16) hsT[4*32*108 + tid] = 0;
  // zero xs padding: cols 26..39 (all rows), rows 104..111 (cols 0..25)
  for (int e = tid; e < 112*14; e += 256){ int r = e/14, c = 26 + e%14; xs[r*40 + c] = 0; }
  for (int e = tid; e < 8*26;  e += 256){ int r = 104 + e/26, c = e%26; xs[r*40 + c] = 0; }
  // load x (fp32 pairs -> packed bf16)
  for (int pp = tid; pp < 1352; pp += 256){
    int b = pp/338, r2 = pp%338, n = r2/13, p = r2%13;
    float2 v = *(const float2*)&x[(b0 + b)*676 + n*26 + 2*p];
    *(u32*)&xs[(b*26 + n)*40 + 2*p] = pack2(v.x, v.y);
  }

  for (int l = 0; l < 3; ++l){
    __syncthreads();

    // ---- matmul1: h_aug = x @ W_aug  (head = w, W frags from global) ----
    {
      s16x8 bfr0 = *(const s16x8*)&wp[((l*4 + w)*32      + lm)*40 + q*8];
      s16x8 bfr1 = *(const s16x8*)&wp[((l*4 + w)*32 + 16 + lm)*40 + q*8];
      #pragma unroll
      for (int t = 0; t < 7; ++t){
        s16x8 af = *(const s16x8*)&xs[(t*16 + lm)*40 + q*8];
        f32x4 z = {0.f,0.f,0.f,0.f};
        f32x4 d0 = MFMA16(af, bfr0, z);
        f32x4 d1 = MFMA16(af, bfr1, z);
        int gr0 = t*16 + q*4;
        if (gr0 < 104){
          { uint2 uu; uu.x = pack2(d0[0], d0[1]); uu.y = pack2(d0[2], d0[3]);
            *(uint2*)&hsT[(w*32 + lm)*108 + gr0] = uu; }
          if (lm < 12){
            uint2 uu; uu.x = pack2(d1[0], d1[1]); uu.y = pack2(d1[2], d1[3]);
            *(uint2*)&hsT[(w*32 + 16 + lm)*108 + gr0] = uu; }
        }
      }
    }
    __syncthreads();

    // ---- matmul2: out^T = h^T @ alpha^T, softmax built in-register (bl = w)
    {
      f32x4 acc00 = {0,0,0,0}, acc01 = acc00, acc10 = acc00, acc11 = acc00;
      const int j0 = q*8;
      const int w26 = w*26;
      #pragma unroll
      for (int h = 0; h < 4; ++h){
        s16x8 am0, am1;
        {
          int base = (h*32 + lm)*108 + w26 + j0;
          uint4 uu = { *(const u32*)&hsT[base],   *(const u32*)&hsT[base+2],
                       *(const u32*)&hsT[base+4], *(const u32*)&hsT[base+6] };
          am0 = __builtin_bit_cast(s16x8, uu);
          base = (h*32 + 16 + lm)*108 + w26 + j0;
          uint4 vv = { *(const u32*)&hsT[base],   *(const u32*)&hsT[base+2],
                       *(const u32*)&hsT[base+4], *(const u32*)&hsT[base+6] };
          am1 = __builtin_bit_cast(s16x8, vv);
        }
        float sd2[8];
        {
          int base = (h*32 + 27)*108 + w26 + j0;
          #pragma unroll
          for (int u = 0; u < 4; ++u){
            u32 v = *(const u32*)&hsT[base + 2*u];
            sd2[2*u]   = bf2f((u16)(v & 0xFFFFu)) * L2E;
            sd2[2*u+1] = bf2f((u16)(v >> 16))     * L2E;
          }
          #pragma unroll
          for (int jj = 0; jj < 8; ++jj)
            if (j0 + jj >= 26) sd2[jj] = -1e30f;   // exp2 -> 0, kills j-pad
        }
        #pragma unroll
        for (int nt = 0; nt < 2; ++nt){
          int i = nt*16 + lm;
          float si2 = bf2f(hsT[(h*32 + 26)*108 + w26 + i]) * L2E;  // i>=26: junk, contained
          float p[8]; float loc = 0.f;
          #pragma unroll
          for (int jj = 0; jj < 8; ++jj){
            float e = si2 + sd2[jj];
            e = fmaxf(e, 0.2f*e);                  // leaky_relu (log2 domain)
            float pv = fexp2(e);
            p[jj] = pv; loc += pv;
          }
          float tot = loc;
          tot += __shfl_xor(tot, 16);
          tot += __shfl_xor(tot, 32);
          float rinv = __builtin_amdgcn_rcpf(tot);
          uint4 bu = { pack2(p[0]*rinv, p[1]*rinv), pack2(p[2]*rinv, p[3]*rinv),
                       pack2(p[4]*rinv, p[5]*rinv), pack2(p[6]*rinv, p[7]*rinv) };
          s16x8 bfrag = __builtin_bit_cast(s16x8, bu);
          if (nt == 0){ acc00 = MFMA16(am0, bfrag, acc00);
                        acc10 = MFMA16(am1, bfrag, acc10); }
          else        { acc01 = MFMA16(am0, bfrag, acc01);
                        acc11 = MFMA16(am1, bfrag, acc11); }
        }
      }
      // epilogue: mean heads (x0.25), ELU, write next-layer xs (bf16)
      #pragma unroll
      for (int nt = 0; nt < 2; ++nt){
        int i = nt*16 + lm;
        if (i < 26){
          int rowb = (w26 + i)*40;
          #pragma unroll
          for (int mt = 0; mt < 2; ++mt){
            f32x4 a = (mt == 0) ? (nt == 0 ? acc00 : acc01)
                                : (nt == 0 ? acc10 : acc11);
            int f0 = mt*16 + q*4;
            float v0 = a[0]*0.25f, v1 = a[1]*0.25f, v2 = a[2]*0.25f, v3 = a[3]*0.25f;
            v0 = (v0 > 0.f) ? v0 : (fexp2(v0*L2E) - 1.f);
            v1 = (v1 > 0.f) ? v1 : (fexp2(v1*L2E) - 1.f);
            v2 = (v2 > 0.f) ? v2 : (fexp2(v2*L2E) - 1.f);
            v3 = (v3 > 0.f) ? v3 : (fexp2(v3*L2E) - 1.f);
            if (f0 <= 20){
              uint2 uu; uu.x = pack2(v0, v1); uu.y = pack2(v2, v3);
              *(uint2*)&xs[rowb + f0] = uu;
            } else if (f0 == 24){
              *(u32*)&xs[rowb + 24] = pack2(v0, v1);
            }
          }
        }
      }
    }
  }
  __syncthreads();
  // store x_final into swizzled A-fragment layout, destination-linear:
  // each 16-thread group writes one contiguous 64B chunk (4 rows x 8 bf16).
  {
    const int mtile = b0 >> 4;
    const int lrow0 = b0 & 15;               // 0,4,8,12
    u16* dstb = xf + (size_t)mtile*22*64*8;
    for (int e = tid; e < 1408; e += 256){
      int chunk = e >> 4;                    // 0..87 = kc*4 + q16
      int u     = e & 15;                    // u32 slot within 64B chunk
      int kc = chunk >> 2, q16 = chunk & 3;
      int bb = u >> 2;                       // local batch 0..3
      int j2 = (u & 3) * 2;
      int k  = kc*32 + q16*8 + j2;           // feature index (0..703, even)
      u32 v = 0;
      if (k < 676){ int n = k/26, f = k - n*26; v = *(const u32*)&xs[(bb*26 + n)*40 + f]; }
      *(u32*)&dstb[((kc*64 + q16*16 + lrow0 + bb) << 3) + j2] = v;
    }
  }
}

// ---------------------------------------------------------------------------
// W1 -> bf16 swizzled B-fragment layout w1_swz[ntile=16][kc=22][lane=64][8].
// grid 352 (one k-pair per block), 256 threads = n. Reads coalesced over n.
// ---------------------------------------------------------------------------
__global__ __launch_bounds__(256) void w1cvt_kernel(const float* __restrict__ W1,
                                                    u16* __restrict__ w1t)
{
  const int k = blockIdx.x * 2;            // 0..702 even
  const int n = threadIdx.x;
  float v0 = 0.f, v1 = 0.f;
  if (k < 676)     v0 = W1[(size_t)k*256 + n];
  if (k + 1 < 676) v1 = W1[(size_t)(k+1)*256 + n];
  const int ntile = n >> 4, lm = n & 15;
  const int kc = k >> 5, q16 = (k >> 3) & 3, j = k & 7;
  u16* dst = w1t + ((((size_t)ntile*22 + kc)*64 + q16*16 + lm) << 3) + j;
  *(u32*)dst = pack2(v0, v1);
}

// ---------------------------------------------------------------------------
// MLP: out = leaky(xf @ W1 + b1, 0.2) @ W2 + b2.  BM=32, grid 512 (2/CU,
// 8 waves/CU). Barrier-free, LDS-free K-loop with explicit 2-stage prefetch;
// all fragments coalesced (1KB/wave) from swizzled layouts. Fused W2 head.
// ---------------------------------------------------------------------------
__global__ __launch_bounds__(256, 2) void mlp_kernel(
    const u16* __restrict__ xf, const u16* __restrict__ w1t,
    const float* __restrict__ b1, const float* __restrict__ w2,
    const float* __restrict__ b2, float* __restrict__ out)
{
  __shared__ float b1s[256];
  __shared__ float w2s[256*3];
  __shared__ float part[4*32*3];

  const int tid  = threadIdx.x;
  const int w    = tid >> 6;
  const int lane = tid & 63;
  const int q    = lane >> 4;
  const int lm   = lane & 15;
  const int m0   = blockIdx.x * 32;
  const int mt0  = blockIdx.x * 2;         // 2 mtiles per block

  b1s[tid] = b1[tid];
  for (int e = tid; e < 768; e += 256) w2s[e] = w2[e];

  f32x4 acc[2][4];
  #pragma unroll
  for (int a = 0; a < 2; ++a)
    #pragma unroll
    for (int b = 0; b < 4; ++b) acc[a][b] = (f32x4){0.f,0.f,0.f,0.f};

  const u16* abase = xf  + ((size_t)mt0*22*64 + lane) * 8;
  const u16* bbase = w1t + (((size_t)w*4)*22*64 + lane) * 8;

  s16x8 af[2], bf[4], afn[2], bfn[4];
  #pragma unroll
  for (int mt = 0; mt < 2; ++mt) af[mt] = *(const s16x8*)(abase + (size_t)(mt*22)*64*8);
  #pragma unroll
  for (int nt = 0; nt < 4; ++nt) bf[nt] = *(const s16x8*)(bbase + (size_t)(nt*22)*64*8);

  #pragma unroll
  for (int kc = 0; kc < 22; ++kc){
    if (kc < 21){
      #pragma unroll
      for (int mt = 0; mt < 2; ++mt)
        afn[mt] = *(const s16x8*)(abase + (size_t)(mt*22 + kc + 1)*64*8);
      #pragma unroll
      for (int nt = 0; nt < 4; ++nt)
        bfn[nt] = *(const s16x8*)(bbase + (size_t)(nt*22 + kc + 1)*64*8);
    }
    #pragma unroll
    for (int mt = 0; mt < 2; ++mt)
      #pragma unroll
      for (int nt = 0; nt < 4; ++nt)
        acc[mt][nt] = MFMA16(af[mt], bf[nt], acc[mt][nt]);
    #pragma unroll
    for (int mt = 0; mt < 2; ++mt) af[mt] = afn[mt];
    #pragma unroll
    for (int nt = 0; nt < 4; ++nt) bf[nt] = bfn[nt];
  }

  // epilogue: +b1, leaky, @W2 partials, reduce over 16 lanes (cols)
  float b1l[4], w2l[4][3];
  #pragma unroll
  for (int nt = 0; nt < 4; ++nt){
    int col = w*64 + nt*16 + lm;
    b1l[nt] = b1s[col];
    w2l[nt][0] = w2s[col*3]; w2l[nt][1] = w2s[col*3+1]; w2l[nt][2] = w2s[col*3+2];
  }
  float po[2][4][3];
  #pragma unroll
  for (int mt = 0; mt < 2; ++mt)
    #pragma unroll
    for (int r = 0; r < 4; ++r){
      float s0 = 0.f, s1 = 0.f, s2 = 0.f;
      #pragma unroll
      for (int nt = 0; nt < 4; ++nt){
        float hv = acc[mt][nt][r] + b1l[nt];
        hv = (hv >= 0.f) ? hv : 0.2f*hv;
        s0 += hv*w2l[nt][0]; s1 += hv*w2l[nt][1]; s2 += hv*w2l[nt][2];
      }
      po[mt][r][0] = s0; po[mt][r][1] = s1; po[mt][r][2] = s2;
    }
  #pragma unroll
  for (int m = 1; m < 16; m <<= 1)
    #pragma unroll
    for (int mt = 0; mt < 2; ++mt)
      #pragma unroll
      for (int r = 0; r < 4; ++r)
        #pragma unroll
        for (int kk = 0; kk < 3; ++kk)
          po[mt][r][kk] += __shfl_xor(po[mt][r][kk], m);
  if (lm == 0){
    #pragma unroll
    for (int mt = 0; mt < 2; ++mt)
      #pragma unroll
      for (int r = 0; r < 4; ++r)
        #pragma unroll
        for (int kk = 0; kk < 3; ++kk)
          part[w*96 + (mt*16 + q*4 + r)*3 + kk] = po[mt][r][kk];
  }
  __syncthreads();
  if (tid < 96){
    int row = tid/3, kk = tid - row*3;
    float o = part[row*3 + kk] + part[96 + row*3 + kk]
            + part[192 + row*3 + kk] + part[288 + row*3 + kk] + b2[kk];
    out[(m0 + row)*3 + kk] = o;
  }
}

extern "C" void kernel_launch(void* const* d_in, const int* in_sizes, int n_in,
                              void* d_out, int out_size, void* d_ws, size_t ws_size,
                              hipStream_t stream)
{
  (void)in_sizes; (void)n_in; (void)out_size; (void)ws_size;
  const float* x     = (const float*)d_in[1];
  const float* W     = (const float*)d_in[2];
  const float* a_src = (const float*)d_in[3];
  const float* a_dst = (const float*)d_in[4];
  const float* W1    = (const float*)d_in[5];
  const float* b1    = (const float*)d_in[6];
  const float* W2    = (const float*)d_in[7];
  const float* b2    = (const float*)d_in[8];
  float* out = (float*)d_out;

  u16* xfinal = (u16*)d_ws;                    // [1024][22][64][8] bf16 (swz)
  u16* w1t    = xfinal + (size_t)16384*704;    // [16][22][64][8]   bf16 (swz)
  u16* wp     = w1t    + 256*704;              // [12][32][40]      bf16

  hipLaunchKernelGGL(wprep_kernel, dim3(12),   dim3(256), 0, stream, W, a_src, a_dst, wp);
  hipLaunchKernelGGL(w1cvt_kernel, dim3(352),  dim3(256), 0, stream, W1, w1t);
  hipLaunchKernelGGL(gat_kernel,   dim3(4096), dim3(256), 0, stream, x, wp, xfinal);
  hipLaunchKernelGGL(mlp_kernel,   dim3(512),  dim3(256), 0, stream, xfinal, w1t, b1, W2, b2, out);
}